// Round 5
// baseline (571.211 us; speedup 1.0000x reference)
//
#include <hip/hip_runtime.h>
#include <hip/hip_bf16.h>

#define N_NODES  100000
#define N_EDGES  640000
#define N_GRAPHS 2048
#define HID      128
#define NB_SCAN  391   // ceil(N_NODES/256)
#define CAP_E    2048  // LDS edge-stage capacity per 64-node tile (mean 410, sigma 20)

// ---------------------------------------------------------------- degree
__global__ void k_deg(const int* __restrict__ col, int* __restrict__ deg) {
    int e = blockIdx.x * blockDim.x + threadIdx.x;
    if (e < N_EDGES) atomicAdd(&deg[col[e]], 1);
}

// ---------------------------------------------------------------- scan (exclusive prefix sum of deg -> row_ptr) + dinv
__global__ void k_scan1(const int* __restrict__ deg, int* __restrict__ row_ptr,
                        int* __restrict__ bsum, float* __restrict__ dinv) {
    __shared__ int s[256];
    int tid = threadIdx.x;
    int i = blockIdx.x * 256 + tid;
    int d = (i < N_NODES) ? deg[i] : 0;
    if (i < N_NODES) dinv[i] = rsqrtf((float)(d + 1));  // +1 self loop
    s[tid] = d;
    __syncthreads();
    for (int off = 1; off < 256; off <<= 1) {
        int v = (tid >= off) ? s[tid - off] : 0;
        __syncthreads();
        s[tid] += v;
        __syncthreads();
    }
    if (i < N_NODES) row_ptr[i] = s[tid] - d;   // exclusive within block
    if (tid == 255) bsum[blockIdx.x] = s[255];
}

__global__ void k_scan2(int* __restrict__ bsum) {
    __shared__ int s[512];
    int tid = threadIdx.x;
    int v = (tid < NB_SCAN) ? bsum[tid] : 0;
    s[tid] = v;
    __syncthreads();
    for (int off = 1; off < 512; off <<= 1) {
        int u = (tid >= off) ? s[tid - off] : 0;
        __syncthreads();
        s[tid] += u;
        __syncthreads();
    }
    if (tid < NB_SCAN) bsum[tid] = s[tid] - v;  // exclusive block offsets
}

__global__ void k_scan3(int* __restrict__ row_ptr, const int* __restrict__ bsum) {
    int i = blockIdx.x * 256 + threadIdx.x;
    if (i < N_NODES) row_ptr[i] += bsum[blockIdx.x];
    if (i == N_NODES) row_ptr[N_NODES] = N_EDGES;
}

// ---------------------------------------------------------------- CSR scatter
__global__ void k_scatter(const int* __restrict__ row, const int* __restrict__ col,
                          const int* __restrict__ row_ptr, int* __restrict__ cursor,
                          const float* __restrict__ dinv, int* __restrict__ src_idx,
                          float* __restrict__ w_edge) {
    int e = blockIdx.x * blockDim.x + threadIdx.x;
    if (e >= N_EDGES) return;
    int c = col[e];
    int r = row[e];
    int p = row_ptr[c] + atomicAdd(&cursor[c], 1);
    src_idx[p] = r;
    w_edge[p] = dinv[r] * dinv[c];
}

// ---------------------------------------------------------------- aggregate x (3 channels)
// init: self-loop term, thread per node
__global__ void k_aggx_init(const float* __restrict__ x, const float* __restrict__ dinv,
                            float* __restrict__ aggx) {
    int i = blockIdx.x * 256 + threadIdx.x;
    if (i >= N_NODES) return;
    float di = dinv[i];
    float sw = di * di;
    aggx[i * 3 + 0] = sw * x[i * 3 + 0];
    aggx[i * 3 + 1] = sw * x[i * 3 + 1];
    aggx[i * 3 + 2] = sw * x[i * 3 + 2];
}

// edge-parallel: atomicAdd into target rows (x, dinv, aggx all L2-resident: ~3 MB)
__global__ void k_aggx_edge(const float* __restrict__ x, const int* __restrict__ row,
                            const int* __restrict__ col, const float* __restrict__ dinv,
                            float* __restrict__ aggx) {
    int e = blockIdx.x * 256 + threadIdx.x;
    if (e >= N_EDGES) return;
    int r = row[e], c = col[e];
    float w = dinv[r] * dinv[c];
    atomicAdd(&aggx[c * 3 + 0], w * x[r * 3 + 0]);
    atomicAdd(&aggx[c * 3 + 1], w * x[r * 3 + 1]);
    atomicAdd(&aggx[c * 3 + 2], w * x[r * 3 + 2]);
}

// ---------------------------------------------------------------- layer-1 dense: aggx[N,3] @ W1[3,128] + b1, relu
__global__ __launch_bounds__(256) void k_fc1(const float* __restrict__ aggx,
                                             const float* __restrict__ W1,
                                             const float* __restrict__ b1,
                                             float* __restrict__ h) {
    int idx = blockIdx.x * 256 + threadIdx.x;
    int node = idx >> 5;
    int cq = idx & 31;
    if (node >= N_NODES) return;
    float x0 = aggx[node * 3 + 0], x1 = aggx[node * 3 + 1], x2 = aggx[node * 3 + 2];
    const float4* W14 = (const float4*)W1;
    float4 w0 = W14[cq], w1 = W14[32 + cq], w2 = W14[64 + cq];
    float4 bb = ((const float4*)b1)[cq];
    float4 o;
    o.x = fmaxf(bb.x + x0 * w0.x + x1 * w1.x + x2 * w2.x, 0.f);
    o.y = fmaxf(bb.y + x0 * w0.y + x1 * w1.y + x2 * w2.y, 0.f);
    o.z = fmaxf(bb.z + x0 * w0.z + x1 * w1.z + x2 * w2.z, 0.f);
    o.w = fmaxf(bb.w + x0 * w0.w + x1 * w1.w + x2 * w2.w, 0.f);
    ((float4*)h)[(size_t)node * 32 + cq] = o;
}

// ---------------------------------------------------------------- fused: aggregate 64 nodes into LDS, then @W+b, relu
// Phase 0: stage this tile's contiguous CSR edge range into LDS (reuses gs space).
// Phase 1: 8 concurrent gather streams/thread; indices via broadcast ds_read_b64;
//          8 row loads in flight (launch_bounds(256,4) -> ~128 VGPR budget).
// Phase 2: dense 128x128 from LDS tile, 8 nodes x 4 channels per thread.
// POOL variant: run-length atomicAdd relu(out) into pooled instead of writing h.
template <bool POOL>
__global__ __launch_bounds__(256, 4) void k_agg_mm(const float* __restrict__ h_in,
                                                   const int* __restrict__ row_ptr,
                                                   const int* __restrict__ src_idx,
                                                   const float* __restrict__ w_edge,
                                                   const float* __restrict__ dinv,
                                                   const float* __restrict__ W,
                                                   const float* __restrict__ b,
                                                   float* __restrict__ h_out,
                                                   const int* __restrict__ batch,
                                                   float* __restrict__ pooled) {
    __shared__ float gs[64][128];
    int2* epair = (int2*)&gs[0][0];   // first 16KB, reclaimed before gs is written
    int tid = threadIdx.x;
    int lane = tid & 31;        // channel quad 0..31
    int slot = tid >> 5;        // 0..7
    int n0 = blockIdx.x * 64;
    int nend = min(n0 + 64, N_NODES);
    const float4* h4 = (const float4*)h_in;

    // ---- phase 0: cooperative edge staging (coalesced)
    int ebase = row_ptr[n0];
    int ecnt = row_ptr[nend] - ebase;
    int ecl = min(ecnt, CAP_E);
    for (int e = tid; e < ecl; e += 256) {
        epair[e] = make_int2(src_idx[ebase + e], __float_as_int(w_edge[ebase + e]));
    }

    // ---- init 8 accumulator streams (self-loop term) + CSR ranges
    float4 acc[8];
    int lbase[8], len[8];
#pragma unroll
    for (int r = 0; r < 8; r++) {
        int m = r * 8 + slot;
        int i = n0 + m;
        bool valid = i < N_NODES;
        int ic = valid ? i : 0;
        int b0 = row_ptr[ic];
        int b1e = row_ptr[ic + 1];
        lbase[r] = b0 - ebase;
        len[r] = valid ? (b1e - b0) : 0;
        float di = dinv[ic];
        float sw = valid ? di * di : 0.f;
        float4 v = h4[(size_t)ic * 32 + lane];
        acc[r].x = sw * v.x; acc[r].y = sw * v.y; acc[r].z = sw * v.z; acc[r].w = sw * v.w;
    }
    int maxlen = len[0];
#pragma unroll
    for (int r = 1; r < 8; r++) maxlen = max(maxlen, len[r]);
    __syncthreads();   // edge stage visible

    // ---- phase 1: edge loop, 8 independent gather streams per thread
    for (int p = 0; p < maxlen; p++) {
        int jj[8];
        float wwt[8];
#pragma unroll
        for (int r = 0; r < 8; r++) {
            int pe = max(min(p, len[r] - 1), 0);
            int le = min(lbase[r] + pe, ecnt - 1);
            bool act = p < len[r];
            int j; float w;
            if (le < CAP_E) {
                int2 pr = epair[le];          // broadcast ds_read_b64
                j = pr.x; w = __int_as_float(pr.y);
            } else {
                j = src_idx[ebase + le];      // overflow fallback (stat. never)
                w = w_edge[ebase + le];
            }
            jj[r] = act ? j : 0;              // inactive -> row 0 (cached)
            wwt[r] = act ? w : 0.f;
        }
#pragma unroll
        for (int r = 0; r < 8; r++) {
            float4 u = h4[(size_t)jj[r] * 32 + lane];
            float w = wwt[r];
            acc[r].x += w * u.x; acc[r].y += w * u.y;
            acc[r].z += w * u.z; acc[r].w += w * u.w;
        }
    }

    __syncthreads();   // all epair reads done; safe to overwrite gs
#pragma unroll
    for (int r = 0; r < 8; r++) {
        int m = r * 8 + slot;
        *(float4*)(&gs[m][lane * 4]) = acc[r];
    }
    __syncthreads();

    // ---- phase 2: dense 128x128
    int cq = tid & 31;          // channel quad
    int mb = tid >> 5;          // node group 0..7
    int c0 = cq * 4;
    float4 bb = *(const float4*)(b + c0);
    float oacc[8][4];
#pragma unroll
    for (int mm = 0; mm < 8; mm++) {
        oacc[mm][0] = bb.x; oacc[mm][1] = bb.y; oacc[mm][2] = bb.z; oacc[mm][3] = bb.w;
    }
    for (int kc = 0; kc < 32; kc++) {
        int k0 = kc * 4;
        float4 w0 = *(const float4*)(W + (k0 + 0) * 128 + c0);
        float4 w1 = *(const float4*)(W + (k0 + 1) * 128 + c0);
        float4 w2 = *(const float4*)(W + (k0 + 2) * 128 + c0);
        float4 w3 = *(const float4*)(W + (k0 + 3) * 128 + c0);
#pragma unroll
        for (int mm = 0; mm < 8; mm++) {
            float4 gv = *(const float4*)(&gs[mb * 8 + mm][k0]);
            oacc[mm][0] += gv.x * w0.x + gv.y * w1.x + gv.z * w2.x + gv.w * w3.x;
            oacc[mm][1] += gv.x * w0.y + gv.y * w1.y + gv.z * w2.y + gv.w * w3.y;
            oacc[mm][2] += gv.x * w0.z + gv.y * w1.z + gv.z * w2.z + gv.w * w3.z;
            oacc[mm][3] += gv.x * w0.w + gv.y * w1.w + gv.z * w2.w + gv.w * w3.w;
        }
    }

    if (!POOL) {
#pragma unroll
        for (int mm = 0; mm < 8; mm++) {
            int node = n0 + mb * 8 + mm;
            if (node < N_NODES) {
                float4 o;
                o.x = fmaxf(oacc[mm][0], 0.f);
                o.y = fmaxf(oacc[mm][1], 0.f);
                o.z = fmaxf(oacc[mm][2], 0.f);
                o.w = fmaxf(oacc[mm][3], 0.f);
                *(float4*)(h_out + (size_t)node * 128 + c0) = o;
            }
        }
    } else {
        // run-length pool over this thread's 8 consecutive (batch-sorted) nodes
        int gcur = -1;
        float p0 = 0.f, p1 = 0.f, p2 = 0.f, p3 = 0.f;
        for (int mm = 0; mm < 8; mm++) {
            int node = n0 + mb * 8 + mm;
            if (node >= N_NODES) break;
            int gb = batch[node];
            if (gb != gcur) {
                if (gcur >= 0) {
                    atomicAdd(&pooled[gcur * 128 + c0 + 0], p0);
                    atomicAdd(&pooled[gcur * 128 + c0 + 1], p1);
                    atomicAdd(&pooled[gcur * 128 + c0 + 2], p2);
                    atomicAdd(&pooled[gcur * 128 + c0 + 3], p3);
                }
                gcur = gb; p0 = p1 = p2 = p3 = 0.f;
            }
            p0 += fmaxf(oacc[mm][0], 0.f);
            p1 += fmaxf(oacc[mm][1], 0.f);
            p2 += fmaxf(oacc[mm][2], 0.f);
            p3 += fmaxf(oacc[mm][3], 0.f);
        }
        if (gcur >= 0) {
            atomicAdd(&pooled[gcur * 128 + c0 + 0], p0);
            atomicAdd(&pooled[gcur * 128 + c0 + 1], p1);
            atomicAdd(&pooled[gcur * 128 + c0 + 2], p2);
            atomicAdd(&pooled[gcur * 128 + c0 + 3], p3);
        }
    }
}

// ---------------------------------------------------------------- final FC: pooled[G,128]/cnt @ Wfc[128,4] + bfc
__global__ void k_final(const float* __restrict__ pooled, const int* __restrict__ batch,
                        const float* __restrict__ Wfc, const float* __restrict__ bfc,
                        float* __restrict__ out) {
    __shared__ float red[128][4];
    __shared__ int cnt_s;
    int g = blockIdx.x, t = threadIdx.x;
    if (t == 0) {
        int lo = 0, hi = N_NODES;
        while (lo < hi) { int mid = (lo + hi) >> 1; if (batch[mid] < g) lo = mid + 1; else hi = mid; }
        int s = lo;
        hi = N_NODES;
        while (lo < hi) { int mid = (lo + hi) >> 1; if (batch[mid] < g + 1) lo = mid + 1; else hi = mid; }
        cnt_s = lo - s;
    }
    __syncthreads();
    float inv = 1.0f / fmaxf((float)cnt_s, 1.0f);
    float v = pooled[g * 128 + t] * inv;
    float4 w = ((const float4*)Wfc)[t];
    red[t][0] = v * w.x; red[t][1] = v * w.y; red[t][2] = v * w.z; red[t][3] = v * w.w;
    __syncthreads();
    for (int s = 64; s > 0; s >>= 1) {
        if (t < s) {
            red[t][0] += red[t + s][0];
            red[t][1] += red[t + s][1];
            red[t][2] += red[t + s][2];
            red[t][3] += red[t + s][3];
        }
        __syncthreads();
    }
    if (t < 4) out[g * 4 + t] = red[0][t] + bfc[t];
}

// ================================================================ launch
extern "C" void kernel_launch(void* const* d_in, const int* in_sizes, int n_in,
                              void* d_out, int out_size, void* d_ws, size_t ws_size,
                              hipStream_t stream) {
    const float* x     = (const float*)d_in[0];
    const int*   ei    = (const int*)d_in[1];
    const int*   row   = ei;             // source
    const int*   col   = ei + N_EDGES;   // target (aggregation side)
    const int*   batch = (const int*)d_in[2];
    const float* W1 = (const float*)d_in[3];
    const float* b1 = (const float*)d_in[4];
    const float* W2 = (const float*)d_in[5];
    const float* b2 = (const float*)d_in[6];
    const float* W3 = (const float*)d_in[7];
    const float* b3 = (const float*)d_in[8];
    const float* W4 = (const float*)d_in[9];
    const float* b4 = (const float*)d_in[10];
    const float* Wfc = (const float*)d_in[11];
    const float* bfc = (const float*)d_in[12];
    float* out = (float*)d_out;

    char* ws = (char*)d_ws;
    size_t off = 0;
    auto take = [&](size_t bytes) -> char* {
        char* p = ws + off;
        off = (off + bytes + 255) & ~(size_t)255;
        return p;
    };
    // deg, cursor, aggx, pooled contiguous -> one memset
    int*   deg     = (int*)take(N_NODES * 4);
    int*   cursor  = (int*)take(N_NODES * 4);
    float* aggx    = (float*)take((size_t)N_NODES * 3 * 4);
    float* pooled  = (float*)take((size_t)N_GRAPHS * 128 * 4);
    size_t zspan   = (size_t)((char*)pooled + (size_t)N_GRAPHS * 128 * 4 - (char*)deg);
    int*   row_ptr = (int*)take((N_NODES + 1) * 4);
    int*   bsum    = (int*)take(512 * 4);
    float* dinv    = (float*)take(N_NODES * 4);
    int*   src_idx = (int*)take(N_EDGES * 4);
    float* w_edge  = (float*)take(N_EDGES * 4);
    float* bufA    = (float*)take((size_t)N_NODES * 128 * 4);
    float* bufB    = (float*)take((size_t)N_NODES * 128 * 4);

    hipMemsetAsync(deg, 0, zspan, stream);

    k_deg<<<(N_EDGES + 255) / 256, 256, 0, stream>>>(col, deg);
    k_scan1<<<NB_SCAN, 256, 0, stream>>>(deg, row_ptr, bsum, dinv);
    k_scan2<<<1, 512, 0, stream>>>(bsum);
    k_scan3<<<NB_SCAN, 256, 0, stream>>>(row_ptr, bsum);
    k_scatter<<<(N_EDGES + 255) / 256, 256, 0, stream>>>(row, col, row_ptr, cursor,
                                                         dinv, src_idx, w_edge);
    k_aggx_init<<<NB_SCAN, 256, 0, stream>>>(x, dinv, aggx);
    k_aggx_edge<<<(N_EDGES + 255) / 256, 256, 0, stream>>>(x, row, col, dinv, aggx);
    k_fc1<<<(N_NODES * 32 + 255) / 256, 256, 0, stream>>>(aggx, W1, b1, bufA);

    const int NBLK = (N_NODES + 63) / 64;
    // layer 2: bufA -> bufB ; layer 3: bufB -> bufA ; layer 4: bufA -> pooled
    k_agg_mm<false><<<NBLK, 256, 0, stream>>>(bufA, row_ptr, src_idx, w_edge, dinv,
                                              W2, b2, bufB, batch, pooled);
    k_agg_mm<false><<<NBLK, 256, 0, stream>>>(bufB, row_ptr, src_idx, w_edge, dinv,
                                              W3, b3, bufA, batch, pooled);
    k_agg_mm<true><<<NBLK, 256, 0, stream>>>(bufA, row_ptr, src_idx, w_edge, dinv,
                                             W4, b4, nullptr, batch, pooled);

    k_final<<<N_GRAPHS, 128, 0, stream>>>(pooled, batch, Wfc, bfc, out);
}

// Round 6
// 469.852 us; speedup vs baseline: 1.2157x; 1.2157x over previous
//
#include <hip/hip_runtime.h>
#include <hip/hip_bf16.h>

#define N_NODES  100000
#define N_EDGES  640000
#define N_GRAPHS 2048
#define HID      128
#define NB_SCAN  391   // ceil(N_NODES/256)
#define CAP_E    2048  // LDS edge-stage capacity per 64-node tile (mean ~410)

// ---------------------------------------------------------------- degree
__global__ void k_deg(const int* __restrict__ col, int* __restrict__ deg) {
    int e = blockIdx.x * blockDim.x + threadIdx.x;
    if (e < N_EDGES) atomicAdd(&deg[col[e]], 1);
}

// ---------------------------------------------------------------- scan (exclusive prefix sum of deg -> row_ptr) + dinv
__global__ void k_scan1(const int* __restrict__ deg, int* __restrict__ row_ptr,
                        int* __restrict__ bsum, float* __restrict__ dinv) {
    __shared__ int s[256];
    int tid = threadIdx.x;
    int i = blockIdx.x * 256 + tid;
    int d = (i < N_NODES) ? deg[i] : 0;
    if (i < N_NODES) dinv[i] = rsqrtf((float)(d + 1));  // +1 self loop
    s[tid] = d;
    __syncthreads();
    for (int off = 1; off < 256; off <<= 1) {
        int v = (tid >= off) ? s[tid - off] : 0;
        __syncthreads();
        s[tid] += v;
        __syncthreads();
    }
    if (i < N_NODES) row_ptr[i] = s[tid] - d;   // exclusive within block
    if (tid == 255) bsum[blockIdx.x] = s[255];
}

__global__ void k_scan2(int* __restrict__ bsum) {
    __shared__ int s[512];
    int tid = threadIdx.x;
    int v = (tid < NB_SCAN) ? bsum[tid] : 0;
    s[tid] = v;
    __syncthreads();
    for (int off = 1; off < 512; off <<= 1) {
        int u = (tid >= off) ? s[tid - off] : 0;
        __syncthreads();
        s[tid] += u;
        __syncthreads();
    }
    if (tid < NB_SCAN) bsum[tid] = s[tid] - v;  // exclusive block offsets
}

__global__ void k_scan3(int* __restrict__ row_ptr, const int* __restrict__ bsum) {
    int i = blockIdx.x * 256 + threadIdx.x;
    if (i < N_NODES) row_ptr[i] += bsum[blockIdx.x];
    if (i == N_NODES) row_ptr[N_NODES] = N_EDGES;
}

// ---------------------------------------------------------------- CSR scatter
__global__ void k_scatter(const int* __restrict__ row, const int* __restrict__ col,
                          const int* __restrict__ row_ptr, int* __restrict__ cursor,
                          const float* __restrict__ dinv, int* __restrict__ src_idx,
                          float* __restrict__ w_edge) {
    int e = blockIdx.x * blockDim.x + threadIdx.x;
    if (e >= N_EDGES) return;
    int c = col[e];
    int r = row[e];
    int p = row_ptr[c] + atomicAdd(&cursor[c], 1);
    src_idx[p] = r;
    w_edge[p] = dinv[r] * dinv[c];
}

// ---------------------------------------------------------------- aggregate x (3 channels), thread per node
__global__ void k_aggx(const float* __restrict__ x, const int* __restrict__ row_ptr,
                       const int* __restrict__ src_idx, const float* __restrict__ w_edge,
                       const float* __restrict__ dinv, float* __restrict__ aggx) {
    int i = blockIdx.x * blockDim.x + threadIdx.x;
    if (i >= N_NODES) return;
    float di = dinv[i];
    float sw = di * di;
    float a0 = sw * x[i * 3 + 0];
    float a1 = sw * x[i * 3 + 1];
    float a2 = sw * x[i * 3 + 2];
    int s = row_ptr[i], e = row_ptr[i + 1];
    for (int k = s; k < e; k++) {
        int j = src_idx[k];
        float w = w_edge[k];
        a0 += w * x[j * 3 + 0];
        a1 += w * x[j * 3 + 1];
        a2 += w * x[j * 3 + 2];
    }
    aggx[i * 3 + 0] = a0;
    aggx[i * 3 + 1] = a1;
    aggx[i * 3 + 2] = a2;
}

// ---------------------------------------------------------------- layer-1 dense: aggx[N,3] @ W1[3,128] + b1, relu
__global__ __launch_bounds__(256) void k_fc1(const float* __restrict__ aggx,
                                             const float* __restrict__ W1,
                                             const float* __restrict__ b1,
                                             float* __restrict__ h) {
    int idx = blockIdx.x * 256 + threadIdx.x;
    int node = idx >> 5;
    int cq = idx & 31;
    if (node >= N_NODES) return;
    float x0 = aggx[node * 3 + 0], x1 = aggx[node * 3 + 1], x2 = aggx[node * 3 + 2];
    const float4* W14 = (const float4*)W1;
    float4 w0 = W14[cq], w1 = W14[32 + cq], w2 = W14[64 + cq];
    float4 bb = ((const float4*)b1)[cq];
    float4 o;
    o.x = fmaxf(bb.x + x0 * w0.x + x1 * w1.x + x2 * w2.x, 0.f);
    o.y = fmaxf(bb.y + x0 * w0.y + x1 * w1.y + x2 * w2.y, 0.f);
    o.z = fmaxf(bb.z + x0 * w0.z + x1 * w1.z + x2 * w2.z, 0.f);
    o.w = fmaxf(bb.w + x0 * w0.w + x1 * w1.w + x2 * w2.w, 0.f);
    ((float4*)h)[(size_t)node * 32 + cq] = o;
}

// ---------------------------------------------------------------- fused: aggregate 64 nodes into LDS, then @W+b, relu
// Phase 0: stage tile's contiguous CSR edge range into LDS (reuses gs space).
// Phase 1: 8 concurrent gather streams/thread. Loads structurally separated
//          from FMAs (u[8] batch) so all 8 global_load_dwordx4 are in flight.
// Phase 2: dense 128x128 from LDS tile, 8 nodes x 4 channels per thread.
// POOL variant: run-length atomicAdd relu(out) into pooled instead of writing h.
template <bool POOL>
__global__ __launch_bounds__(256, 4) void k_agg_mm(const float* __restrict__ h_in,
                                                   const int* __restrict__ row_ptr,
                                                   const int* __restrict__ src_idx,
                                                   const float* __restrict__ w_edge,
                                                   const float* __restrict__ dinv,
                                                   const float* __restrict__ W,
                                                   const float* __restrict__ b,
                                                   float* __restrict__ h_out,
                                                   const int* __restrict__ batch,
                                                   float* __restrict__ pooled) {
    __shared__ float gs[64][128];
    int2* epair = (int2*)&gs[0][0];   // first 16KB, reclaimed before gs is written
    int tid = threadIdx.x;
    int lane = tid & 31;        // channel quad 0..31
    int slot = tid >> 5;        // 0..7
    int n0 = blockIdx.x * 64;
    int nend = min(n0 + 64, N_NODES);
    const float4* h4 = (const float4*)h_in;

    // ---- phase 0: cooperative edge staging (coalesced)
    int ebase = row_ptr[n0];
    int ecnt = row_ptr[nend] - ebase;
    int ecl = min(ecnt, CAP_E);
    for (int e = tid; e < ecl; e += 256) {
        epair[e] = make_int2(src_idx[ebase + e], __float_as_int(w_edge[ebase + e]));
    }

    // ---- init 8 accumulator streams (self-loop term) + CSR ranges
    float4 acc[8];
    int lbase[8], len[8];
#pragma unroll
    for (int r = 0; r < 8; r++) {
        int m = r * 8 + slot;
        int i = n0 + m;
        bool valid = i < N_NODES;
        int ic = valid ? i : 0;
        int b0 = row_ptr[ic];
        int b1e = row_ptr[ic + 1];
        lbase[r] = valid ? (b0 - ebase) : 0;
        len[r] = valid ? (b1e - b0) : 0;
        float di = dinv[ic];
        float sw = valid ? di * di : 0.f;
        float4 v = h4[(size_t)ic * 32 + lane];
        acc[r].x = sw * v.x; acc[r].y = sw * v.y; acc[r].z = sw * v.z; acc[r].w = sw * v.w;
    }
    int maxlen = len[0];
#pragma unroll
    for (int r = 1; r < 8; r++) maxlen = max(maxlen, len[r]);
    __syncthreads();   // edge stage visible

    // ---- phase 1: edge loop, 8 independent gather streams per thread.
    // Block-uniform branch: hot path indexes LDS only (ecnt <= CAP_E).
    if (ecnt <= CAP_E) {
        for (int p = 0; p < maxlen; p++) {
            int jj[8];
            float wwt[8];
#pragma unroll
            for (int r = 0; r < 8; r++) {
                int pe = max(min(p, len[r] - 1), 0);
                int2 pr = epair[lbase[r] + pe];   // broadcast ds_read_b64
                bool act = p < len[r];
                jj[r] = act ? pr.x : 0;           // inactive -> row 0 (cached)
                wwt[r] = act ? __int_as_float(pr.y) : 0.f;
            }
            float4 u[8];
#pragma unroll
            for (int r = 0; r < 8; r++) {         // 8 loads issued back-to-back
                u[r] = h4[(size_t)jj[r] * 32 + lane];
            }
#pragma unroll
            for (int r = 0; r < 8; r++) {
                float w = wwt[r];
                acc[r].x += w * u[r].x; acc[r].y += w * u[r].y;
                acc[r].z += w * u[r].z; acc[r].w += w * u[r].w;
            }
        }
    } else {
        for (int p = 0; p < maxlen; p++) {
            int jj[8];
            float wwt[8];
#pragma unroll
            for (int r = 0; r < 8; r++) {
                int pe = max(min(p, len[r] - 1), 0);
                int idx = ebase + lbase[r] + pe;
                bool act = p < len[r];
                int j = src_idx[idx];
                float w = w_edge[idx];
                jj[r] = act ? j : 0;
                wwt[r] = act ? w : 0.f;
            }
            float4 u[8];
#pragma unroll
            for (int r = 0; r < 8; r++) {
                u[r] = h4[(size_t)jj[r] * 32 + lane];
            }
#pragma unroll
            for (int r = 0; r < 8; r++) {
                float w = wwt[r];
                acc[r].x += w * u[r].x; acc[r].y += w * u[r].y;
                acc[r].z += w * u[r].z; acc[r].w += w * u[r].w;
            }
        }
    }

    __syncthreads();   // all epair reads done; safe to overwrite gs
#pragma unroll
    for (int r = 0; r < 8; r++) {
        int m = r * 8 + slot;
        *(float4*)(&gs[m][lane * 4]) = acc[r];
    }
    __syncthreads();

    // ---- phase 2: dense 128x128
    int cq = tid & 31;          // channel quad
    int mb = tid >> 5;          // node group 0..7
    int c0 = cq * 4;
    float4 bb = *(const float4*)(b + c0);
    float oacc[8][4];
#pragma unroll
    for (int mm = 0; mm < 8; mm++) {
        oacc[mm][0] = bb.x; oacc[mm][1] = bb.y; oacc[mm][2] = bb.z; oacc[mm][3] = bb.w;
    }
    for (int kc = 0; kc < 32; kc++) {
        int k0 = kc * 4;
        float4 w0 = *(const float4*)(W + (k0 + 0) * 128 + c0);
        float4 w1 = *(const float4*)(W + (k0 + 1) * 128 + c0);
        float4 w2 = *(const float4*)(W + (k0 + 2) * 128 + c0);
        float4 w3 = *(const float4*)(W + (k0 + 3) * 128 + c0);
#pragma unroll
        for (int mm = 0; mm < 8; mm++) {
            float4 gv = *(const float4*)(&gs[mb * 8 + mm][k0]);
            oacc[mm][0] += gv.x * w0.x + gv.y * w1.x + gv.z * w2.x + gv.w * w3.x;
            oacc[mm][1] += gv.x * w0.y + gv.y * w1.y + gv.z * w2.y + gv.w * w3.y;
            oacc[mm][2] += gv.x * w0.z + gv.y * w1.z + gv.z * w2.z + gv.w * w3.z;
            oacc[mm][3] += gv.x * w0.w + gv.y * w1.w + gv.z * w2.w + gv.w * w3.w;
        }
    }

    if (!POOL) {
#pragma unroll
        for (int mm = 0; mm < 8; mm++) {
            int node = n0 + mb * 8 + mm;
            if (node < N_NODES) {
                float4 o;
                o.x = fmaxf(oacc[mm][0], 0.f);
                o.y = fmaxf(oacc[mm][1], 0.f);
                o.z = fmaxf(oacc[mm][2], 0.f);
                o.w = fmaxf(oacc[mm][3], 0.f);
                *(float4*)(h_out + (size_t)node * 128 + c0) = o;
            }
        }
    } else {
        // run-length pool over this thread's 8 consecutive (batch-sorted) nodes
        int gcur = -1;
        float p0 = 0.f, p1 = 0.f, p2 = 0.f, p3 = 0.f;
        for (int mm = 0; mm < 8; mm++) {
            int node = n0 + mb * 8 + mm;
            if (node >= N_NODES) break;
            int gb = batch[node];
            if (gb != gcur) {
                if (gcur >= 0) {
                    atomicAdd(&pooled[gcur * 128 + c0 + 0], p0);
                    atomicAdd(&pooled[gcur * 128 + c0 + 1], p1);
                    atomicAdd(&pooled[gcur * 128 + c0 + 2], p2);
                    atomicAdd(&pooled[gcur * 128 + c0 + 3], p3);
                }
                gcur = gb; p0 = p1 = p2 = p3 = 0.f;
            }
            p0 += fmaxf(oacc[mm][0], 0.f);
            p1 += fmaxf(oacc[mm][1], 0.f);
            p2 += fmaxf(oacc[mm][2], 0.f);
            p3 += fmaxf(oacc[mm][3], 0.f);
        }
        if (gcur >= 0) {
            atomicAdd(&pooled[gcur * 128 + c0 + 0], p0);
            atomicAdd(&pooled[gcur * 128 + c0 + 1], p1);
            atomicAdd(&pooled[gcur * 128 + c0 + 2], p2);
            atomicAdd(&pooled[gcur * 128 + c0 + 3], p3);
        }
    }
}

// ---------------------------------------------------------------- final FC: pooled[G,128]/cnt @ Wfc[128,4] + bfc
__global__ void k_final(const float* __restrict__ pooled, const int* __restrict__ batch,
                        const float* __restrict__ Wfc, const float* __restrict__ bfc,
                        float* __restrict__ out) {
    __shared__ float red[128][4];
    __shared__ int cnt_s;
    int g = blockIdx.x, t = threadIdx.x;
    if (t == 0) {
        int lo = 0, hi = N_NODES;
        while (lo < hi) { int mid = (lo + hi) >> 1; if (batch[mid] < g) lo = mid + 1; else hi = mid; }
        int s = lo;
        hi = N_NODES;
        while (lo < hi) { int mid = (lo + hi) >> 1; if (batch[mid] < g + 1) lo = mid + 1; else hi = mid; }
        cnt_s = lo - s;
    }
    __syncthreads();
    float inv = 1.0f / fmaxf((float)cnt_s, 1.0f);
    float v = pooled[g * 128 + t] * inv;
    float4 w = ((const float4*)Wfc)[t];
    red[t][0] = v * w.x; red[t][1] = v * w.y; red[t][2] = v * w.z; red[t][3] = v * w.w;
    __syncthreads();
    for (int s = 64; s > 0; s >>= 1) {
        if (t < s) {
            red[t][0] += red[t + s][0];
            red[t][1] += red[t + s][1];
            red[t][2] += red[t + s][2];
            red[t][3] += red[t + s][3];
        }
        __syncthreads();
    }
    if (t < 4) out[g * 4 + t] = red[0][t] + bfc[t];
}

// ================================================================ launch
extern "C" void kernel_launch(void* const* d_in, const int* in_sizes, int n_in,
                              void* d_out, int out_size, void* d_ws, size_t ws_size,
                              hipStream_t stream) {
    const float* x     = (const float*)d_in[0];
    const int*   ei    = (const int*)d_in[1];
    const int*   row   = ei;             // source
    const int*   col   = ei + N_EDGES;   // target (aggregation side)
    const int*   batch = (const int*)d_in[2];
    const float* W1 = (const float*)d_in[3];
    const float* b1 = (const float*)d_in[4];
    const float* W2 = (const float*)d_in[5];
    const float* b2 = (const float*)d_in[6];
    const float* W3 = (const float*)d_in[7];
    const float* b3 = (const float*)d_in[8];
    const float* W4 = (const float*)d_in[9];
    const float* b4 = (const float*)d_in[10];
    const float* Wfc = (const float*)d_in[11];
    const float* bfc = (const float*)d_in[12];
    float* out = (float*)d_out;

    char* ws = (char*)d_ws;
    size_t off = 0;
    auto take = [&](size_t bytes) -> char* {
        char* p = ws + off;
        off = (off + bytes + 255) & ~(size_t)255;
        return p;
    };
    // deg, cursor, pooled contiguous -> one memset
    int*   deg     = (int*)take(N_NODES * 4);
    int*   cursor  = (int*)take(N_NODES * 4);
    float* pooled  = (float*)take((size_t)N_GRAPHS * 128 * 4);
    size_t zspan   = (size_t)((char*)pooled + (size_t)N_GRAPHS * 128 * 4 - (char*)deg);
    int*   row_ptr = (int*)take((N_NODES + 1) * 4);
    int*   bsum    = (int*)take(512 * 4);
    float* dinv    = (float*)take(N_NODES * 4);
    float* aggx    = (float*)take((size_t)N_NODES * 3 * 4);
    int*   src_idx = (int*)take(N_EDGES * 4);
    float* w_edge  = (float*)take(N_EDGES * 4);
    float* bufA    = (float*)take((size_t)N_NODES * 128 * 4);
    float* bufB    = (float*)take((size_t)N_NODES * 128 * 4);

    hipMemsetAsync(deg, 0, zspan, stream);

    k_deg<<<(N_EDGES + 255) / 256, 256, 0, stream>>>(col, deg);
    k_scan1<<<NB_SCAN, 256, 0, stream>>>(deg, row_ptr, bsum, dinv);
    k_scan2<<<1, 512, 0, stream>>>(bsum);
    k_scan3<<<NB_SCAN, 256, 0, stream>>>(row_ptr, bsum);
    k_scatter<<<(N_EDGES + 255) / 256, 256, 0, stream>>>(row, col, row_ptr, cursor,
                                                         dinv, src_idx, w_edge);
    k_aggx<<<NB_SCAN, 256, 0, stream>>>(x, row_ptr, src_idx, w_edge, dinv, aggx);
    k_fc1<<<(N_NODES * 32 + 255) / 256, 256, 0, stream>>>(aggx, W1, b1, bufA);

    const int NBLK = (N_NODES + 63) / 64;
    // layer 2: bufA -> bufB ; layer 3: bufB -> bufA ; layer 4: bufA -> pooled
    k_agg_mm<false><<<NBLK, 256, 0, stream>>>(bufA, row_ptr, src_idx, w_edge, dinv,
                                              W2, b2, bufB, batch, pooled);
    k_agg_mm<false><<<NBLK, 256, 0, stream>>>(bufB, row_ptr, src_idx, w_edge, dinv,
                                              W3, b3, bufA, batch, pooled);
    k_agg_mm<true><<<NBLK, 256, 0, stream>>>(bufA, row_ptr, src_idx, w_edge, dinv,
                                             W4, b4, nullptr, batch, pooled);

    k_final<<<N_GRAPHS, 128, 0, stream>>>(pooled, batch, Wfc, bfc, out);
}